// Round 3
// baseline (773.860 us; speedup 1.0000x reference)
//
#include <hip/hip_runtime.h>
#include <cstdint>
#include <cstddef>

typedef unsigned short u16;
using bf16x8  = __attribute__((ext_vector_type(8))) short;
using floatx4 = __attribute__((ext_vector_type(4))) float;

// ---------- helpers ----------
__device__ __forceinline__ u16 f2bf(float f) {
    union { float f; unsigned u; } v; v.f = f;
    unsigned r = v.u + 0x7fffu + ((v.u >> 16) & 1u);   // RNE
    return (u16)(r >> 16);
}
__device__ __forceinline__ float bf2f(u16 h) {
    union { unsigned u; float f; } v; v.u = ((unsigned)h) << 16; return v.f;
}
__device__ __forceinline__ floatx4 mfma16(bf16x8 a, bf16x8 b, floatx4 c) {
    return __builtin_amdgcn_mfma_f32_16x16x32_bf16(a, b, c, 0, 0, 0);
}
using gptr_t = const __attribute__((address_space(1))) unsigned int*;
using lptr_t = __attribute__((address_space(3))) unsigned int*;
__device__ __forceinline__ void lds16(const void* g, void* l) {
    __builtin_amdgcn_global_load_lds((gptr_t)g, (lptr_t)l, 16, 0, 0);
}

#define ATT_SCALE 0.1275758218522532f   // log2(e) / sqrt(128)

// ---------- 1. convert x f32 -> bf16 ----------
__global__ __launch_bounds__(256) void cvt_x(const float* __restrict__ x, u16* __restrict__ xb) {
    size_t i = ((size_t)blockIdx.x * 256 + threadIdx.x) * 4;
    float4 v = *(const float4*)&x[i];
    ushort4 r; r.x = f2bf(v.x); r.y = f2bf(v.y); r.z = f2bf(v.z); r.w = f2bf(v.w);
    *(ushort4*)&xb[i] = r;
}

// ---------- 2. transpose+convert all 4 weights f32 [2048][2048] -> bf16 [n][k] ----------
__global__ __launch_bounds__(256) void transpose_wall(const float* __restrict__ wq, const float* __restrict__ wk,
                                                      const float* __restrict__ wv, const float* __restrict__ wo,
                                                      u16* __restrict__ wqkvb, u16* __restrict__ wob) {
    __shared__ float t[64][65];
    const int z = blockIdx.z;
    const float* in = (z == 0) ? wq : (z == 1) ? wk : (z == 2) ? wv : wo;
    u16* out = (z < 3) ? (wqkvb + (size_t)z * 2048 * 2048) : wob;
    int k0 = blockIdx.x * 64, n0 = blockIdx.y * 64;
    int tx = threadIdx.x, ty = threadIdx.y;   // (64,4)
#pragma unroll
    for (int i = 0; i < 16; ++i) {
        int r = i * 4 + ty;
        t[r][tx] = in[(size_t)(k0 + r) * 2048 + n0 + tx];
    }
    __syncthreads();
#pragma unroll
    for (int i = 0; i < 16; ++i) {
        int r = i * 4 + ty;
        out[(size_t)(n0 + r) * 2048 + k0 + tx] = f2bf(t[tx][r]);
    }
}

// ---------- 3. main GEMM (A[m][k] bf16, B^T[n][k] bf16), 128x128 tile, BK=64 ----------
// MODE 0: QKV projection; RoPE fused into epilogue for Q/K (Q also pre-scaled); V remapped store.
// MODE 1: output projection, f32 into d_out.
template <int MODE>
__global__ __launch_bounds__(256) void gemm_bt(const u16* __restrict__ A, const u16* __restrict__ B,
                                               u16* __restrict__ Qo, u16* __restrict__ Ko, u16* __restrict__ Vo,
                                               float* __restrict__ Co,
                                               const float* __restrict__ cosb, const float* __restrict__ sinb) {
    __shared__ __align__(16) u16 As[128 * 64];
    __shared__ __align__(16) u16 Bs[128 * 64];
    const int m0 = blockIdx.y << 7;
    const int n0 = blockIdx.x << 7;
    const int tid = threadIdx.x;
    const int w = tid >> 6, lane = tid & 63;
    const int wm = w >> 1, wn = w & 1;
    const int m16 = lane & 15, q4 = lane >> 4;

    // B-fragment column mapping: MODE 0 pairs (d, d+64) within a wave for RoPE
    int nsel[4];
#pragma unroll
    for (int c = 0; c < 4; ++c)
        nsel[c] = (MODE == 0) ? ((c >> 1) * 64 + wn * 32 + ((c & 1) << 4) + m16)
                              : (wn * 64 + c * 16 + m16);

    floatx4 acc[4][4];
#pragma unroll
    for (int r = 0; r < 4; ++r)
#pragma unroll
        for (int c = 0; c < 4; ++c) acc[r][c] = (floatx4)0.0f;

    const u16* Abase = A + (size_t)(m0 + w * 32 + (lane >> 3)) * 2048 + (lane & 7) * 8;
    const u16* Bbase = B + (size_t)(n0 + w * 32 + (lane >> 3)) * 2048 + (lane & 7) * 8;
    u16* lA = As + (w * 32) * 64;
    u16* lB = Bs + (w * 32) * 64;

    for (int kt = 0; kt < 32; ++kt) {
        __syncthreads();
        const u16* ga = Abase + kt * 64;
        const u16* gb = Bbase + kt * 64;
#pragma unroll
        for (int t = 0; t < 4; ++t) {
            lds16(ga + (size_t)t * 8 * 2048, lA + t * 8 * 64);
            lds16(gb + (size_t)t * 8 * 2048, lB + t * 8 * 64);
        }
        __syncthreads();
#pragma unroll
        for (int kk = 0; kk < 2; ++kk) {
            bf16x8 af[4], bfr[4];
#pragma unroll
            for (int r = 0; r < 4; ++r)
                af[r] = *(const bf16x8*)&As[(wm * 64 + r * 16 + m16) * 64 + kk * 32 + q4 * 8];
#pragma unroll
            for (int c = 0; c < 4; ++c)
                bfr[c] = *(const bf16x8*)&Bs[nsel[c] * 64 + kk * 32 + q4 * 8];
#pragma unroll
            for (int r = 0; r < 4; ++r)
#pragma unroll
                for (int c = 0; c < 4; ++c)
                    acc[r][c] = mfma16(af[r], bfr[c], acc[r][c]);
        }
    }

    if (MODE == 0) {
        const int which = n0 >> 11;
        const int h = (n0 >> 7) & 15;
        u16* dst = (which == 0) ? Qo : ((which == 1) ? Ko : Vo);
        if (which < 2) {
            const float sc = (which == 0) ? ATT_SCALE : 1.0f;
#pragma unroll
            for (int r = 0; r < 4; ++r) {
#pragma unroll
                for (int i = 0; i < 4; ++i) {
                    int mm = m0 + wm * 64 + r * 16 + q4 * 4 + i;
                    int b = mm >> 11, s = mm & 2047;
                    size_t rowbase = ((size_t)((b * 16 + h) * 2048 + s)) << 7;
#pragma unroll
                    for (int cp = 0; cp < 2; ++cp) {
                        int d63 = wn * 32 + cp * 16 + m16;
                        float cs = cosb[s * 64 + d63], sn = sinb[s * 64 + d63];
                        float lo = acc[r][cp][i], hi = acc[r][cp + 2][i];
                        dst[rowbase + d63]      = f2bf((lo * cs - hi * sn) * sc);
                        dst[rowbase + d63 + 64] = f2bf((hi * cs + lo * sn) * sc);
                    }
                }
            }
        } else {
#pragma unroll
            for (int r = 0; r < 4; ++r) {
#pragma unroll
                for (int c = 0; c < 4; ++c) {
                    int d = (c >> 1) * 64 + wn * 32 + ((c & 1) << 4) + m16;
                    int mbase = m0 + wm * 64 + r * 16 + q4 * 4;
#pragma unroll
                    for (int i = 0; i < 4; ++i) {
                        int mm = mbase + i;
                        int b = mm >> 11, s = mm & 2047;
                        dst[((size_t)((b * 16 + h) * 2048 + s) << 7) + d] = f2bf(acc[r][c][i]);
                    }
                }
            }
        }
    } else {
#pragma unroll
        for (int r = 0; r < 4; ++r) {
#pragma unroll
            for (int c = 0; c < 4; ++c) {
                int n = n0 + wn * 64 + c * 16 + m16;
                int mbase = m0 + wm * 64 + r * 16 + q4 * 4;
#pragma unroll
                for (int i = 0; i < 4; ++i)
                    Co[(size_t)(mbase + i) * 2048 + n] = acc[r][c][i];
            }
        }
    }
}

// ---------- 4. transpose V [b,h][2048][128] -> V^T [b,h][128][2048] ----------
__global__ __launch_bounds__(256) void transpose_v(const u16* __restrict__ V, u16* __restrict__ VT) {
    __shared__ u16 t[64][65];
    int bh = blockIdx.z;
    const u16* in = V + (size_t)bh * 2048 * 128;
    u16* out = VT + (size_t)bh * 128 * 2048;
    int s0 = blockIdx.x * 64, d0 = blockIdx.y * 64;
    int tx = threadIdx.x, ty = threadIdx.y;
#pragma unroll
    for (int i = 0; i < 16; ++i) {
        int r = i * 4 + ty;
        t[r][tx] = in[(size_t)(s0 + r) * 128 + d0 + tx];
    }
    __syncthreads();
#pragma unroll
    for (int i = 0; i < 16; ++i) {
        int r = i * 4 + ty;
        out[(size_t)(d0 + r) * 2048 + s0 + tx] = t[tx][r];
    }
}

// ---------- 5. flash attention v3: 256 thr / 4 waves, 32 q-rows per wave ----------
// K-tile ping-pong (1 barrier/iter, register prefetch); V^T read direct from global (L1/L2);
// S^T = K Q^T lane-local softmax. Q pre-scaled. AO: [b,s,h*128+d]
__global__ __launch_bounds__(256, 2) void attn_kernel(const u16* __restrict__ Q, const u16* __restrict__ K,
                                                      const u16* __restrict__ VT, u16* __restrict__ AO) {
    __shared__ __align__(16) u16 ks[2][64 * 136];  // K-tile dbuf [k 64][d 128+8]
    __shared__ __align__(16) u16 ps[128 * 72];     // P [q 128][k 64+8]
    const int bx = blockIdx.x;
    const int iq = 15 - (bx >> 6);                 // heavy-first
    const int bh = bx & 63;
    const int b = bh >> 4, h = bh & 15;
    const u16* Qg = Q  + (size_t)bh * (2048 * 128);
    const u16* Kg = K  + (size_t)bh * (2048 * 128);
    const u16* Vg = VT + (size_t)bh * (128 * 2048);
    const int tid = threadIdx.x, w = tid >> 6, lane = tid & 63;
    const int m16 = lane & 15, q4 = lane >> 4;
    const int jn = 2 * iq + 2;

    // wave w owns q-rows [iq*128 + w*32, +32): two 16-row tiles (rm)
    const int qrow = iq * 128 + w * 32;
    bf16x8 qf[2][4];
#pragma unroll
    for (int rm = 0; rm < 2; ++rm)
#pragma unroll
        for (int kk = 0; kk < 4; ++kk)
            qf[rm][kk] = *(const bf16x8*)&Qg[(size_t)(qrow + rm * 16 + m16) * 128 + kk * 32 + q4 * 8];

    floatx4 o[2][8];
#pragma unroll
    for (int rm = 0; rm < 2; ++rm)
#pragma unroll
        for (int c = 0; c < 8; ++c) o[rm][c] = (floatx4)0.0f;
    float mrow[2] = {-1e30f, -1e30f}, lrow[2] = {0.0f, 0.0f};

    // K staging: 1024 chunks of 16B; 4 per thread. chunk id = u*256+tid -> row id>>4, col id&15
    uint4 kreg[4];
#pragma unroll
    for (int u = 0; u < 4; ++u) {
        int id = u * 256 + tid;
        kreg[u] = *(const uint4*)&Kg[(size_t)(id >> 4) * 128 + (id & 15) * 8];
    }
    {   // store tile 0 -> buf0, prefetch tile 1
#pragma unroll
        for (int u = 0; u < 4; ++u) {
            int id = u * 256 + tid;
            *(uint4*)&ks[0][(id >> 4) * 136 + (id & 15) * 8] = kreg[u];
        }
        int j1 = (1 < jn) ? 1 : 0;
#pragma unroll
        for (int u = 0; u < 4; ++u) {
            int id = u * 256 + tid;
            kreg[u] = *(const uint4*)&Kg[(size_t)(j1 * 64 + (id >> 4)) * 128 + (id & 15) * 8];
        }
    }
    __syncthreads();

    for (int j = 0; j < jn; ++j) {
        const int cur = j & 1;
        // store prefetched tile j+1 into the other buffer; issue loads for j+2
        if (j + 1 < jn) {
#pragma unroll
            for (int u = 0; u < 4; ++u) {
                int id = u * 256 + tid;
                *(uint4*)&ks[1 - cur][(id >> 4) * 136 + (id & 15) * 8] = kreg[u];
            }
            int j2 = (j + 2 < jn) ? (j + 2) : (jn - 1);
#pragma unroll
            for (int u = 0; u < 4; ++u) {
                int id = u * 256 + tid;
                kreg[u] = *(const uint4*)&Kg[(size_t)(j2 * 64 + (id >> 4)) * 128 + (id & 15) * 8];
            }
        }

        // S^T = K Q^T : rows k (4 tiles of 16), cols q (16 per rm)
        floatx4 sacc[2][4];
#pragma unroll
        for (int rm = 0; rm < 2; ++rm)
#pragma unroll
            for (int r = 0; r < 4; ++r) sacc[rm][r] = (floatx4)0.0f;
#pragma unroll
        for (int kk = 0; kk < 4; ++kk) {
            bf16x8 kb[4];
#pragma unroll
            for (int r = 0; r < 4; ++r)
                kb[r] = *(const bf16x8*)&ks[cur][(r * 16 + m16) * 136 + kk * 32 + q4 * 8];
#pragma unroll
            for (int rm = 0; rm < 2; ++rm)
#pragma unroll
                for (int r = 0; r < 4; ++r)
                    sacc[rm][r] = mfma16(kb[r], qf[rm][kk], sacc[rm][r]);
        }

        // causal mask: lane holds S^T[k = j*64 + r*16 + q4*4 + i][q = qrow + rm*16 + m16]
        if (j >= 2 * iq) {
#pragma unroll
            for (int rm = 0; rm < 2; ++rm) {
                const int qg = qrow + rm * 16 + m16;
#pragma unroll
                for (int r = 0; r < 4; ++r)
#pragma unroll
                    for (int i = 0; i < 4; ++i) {
                        int kg = j * 64 + r * 16 + q4 * 4 + i;
                        if (kg > qg) sacc[rm][r][i] = -1e30f;
                    }
            }
        }

#pragma unroll
        for (int rm = 0; rm < 2; ++rm) {
            float pmax = -1e30f;
#pragma unroll
            for (int r = 0; r < 4; ++r)
#pragma unroll
                for (int i = 0; i < 4; ++i) pmax = fmaxf(pmax, sacc[rm][r][i]);
            pmax = fmaxf(pmax, __shfl_xor(pmax, 16));
            pmax = fmaxf(pmax, __shfl_xor(pmax, 32));
            float mnew = fmaxf(mrow[rm], pmax);
            float alpha = __builtin_amdgcn_exp2f(mrow[rm] - mnew);
            mrow[rm] = mnew;

            float psum = 0.0f;
#pragma unroll
            for (int r = 0; r < 4; ++r) {
                float p0 = __builtin_amdgcn_exp2f(sacc[rm][r][0] - mnew);
                float p1 = __builtin_amdgcn_exp2f(sacc[rm][r][1] - mnew);
                float p2 = __builtin_amdgcn_exp2f(sacc[rm][r][2] - mnew);
                float p3 = __builtin_amdgcn_exp2f(sacc[rm][r][3] - mnew);
                psum += (p0 + p1) + (p2 + p3);
                ushort4 pk; pk.x = f2bf(p0); pk.y = f2bf(p1); pk.z = f2bf(p2); pk.w = f2bf(p3);
                *(ushort4*)&ps[(w * 32 + rm * 16 + m16) * 72 + r * 16 + q4 * 4] = pk;
            }
            psum += __shfl_xor(psum, 16);
            psum += __shfl_xor(psum, 32);
            lrow[rm] = lrow[rm] * alpha + psum;

            float abc[4];
#pragma unroll
            for (int i = 0; i < 4; ++i) abc[i] = __shfl(alpha, q4 * 4 + i);
#pragma unroll
            for (int c = 0; c < 8; ++c)
#pragma unroll
                for (int i = 0; i < 4; ++i) o[rm][c][i] *= abc[i];
        }

        // O += P V : P from LDS (wave-private rows), V^T fragments direct from global
#pragma unroll
        for (int kk = 0; kk < 2; ++kk) {
            bf16x8 pa[2], vb[8];
#pragma unroll
            for (int rm = 0; rm < 2; ++rm)
                pa[rm] = *(const bf16x8*)&ps[(w * 32 + rm * 16 + m16) * 72 + kk * 32 + q4 * 8];
#pragma unroll
            for (int c = 0; c < 8; ++c)
                vb[c] = *(const bf16x8*)&Vg[(size_t)(c * 16 + m16) * 2048 + j * 64 + kk * 32 + q4 * 8];
#pragma unroll
            for (int rm = 0; rm < 2; ++rm)
#pragma unroll
                for (int c = 0; c < 8; ++c)
                    o[rm][c] = mfma16(pa[rm], vb[c], o[rm][c]);
        }
        __syncthreads();   // single barrier per iter: K stores (j+1) visible, buf[cur] reads done
    }

    // epilogue: O row = q4*4+i (q-local), col d = c*16+m16; l lives at lane m16=q -> shfl
#pragma unroll
    for (int rm = 0; rm < 2; ++rm) {
        float linv = __builtin_amdgcn_rcpf(lrow[rm]);
        float li[4];
#pragma unroll
        for (int i = 0; i < 4; ++i) li[i] = __shfl(linv, q4 * 4 + i);
#pragma unroll
        for (int c = 0; c < 8; ++c)
#pragma unroll
            for (int i = 0; i < 4; ++i) {
                int s = qrow + rm * 16 + q4 * 4 + i;
                int d = c * 16 + m16;
                AO[((size_t)(b * 2048 + s)) * 2048 + h * 128 + d] = f2bf(o[rm][c][i] * li[i]);
            }
    }
}

// ---------- launch ----------
extern "C" void kernel_launch(void* const* d_in, const int* in_sizes, int n_in,
                              void* d_out, int out_size, void* d_ws, size_t ws_size,
                              hipStream_t stream) {
    const float* x    = (const float*)d_in[0];
    const float* wq   = (const float*)d_in[1];
    const float* wk   = (const float*)d_in[2];
    const float* wv   = (const float*)d_in[3];
    const float* wo   = (const float*)d_in[4];
    const float* cosb = (const float*)d_in[5];
    const float* sinb = (const float*)d_in[6];
    float* out = (float*)d_out;

    char* ws = (char*)d_ws;
    u16* xb    = (u16*)(ws);
    u16* AO    = xb;                                  // alias: xb dead after QKV GEMM
    u16* wqkvb = (u16*)(ws + 33554432);
    u16* wob   = (u16*)(ws + 58720256);
    u16* Qb    = (u16*)(ws + 67108864);
    u16* Kb    = (u16*)(ws + 100663296);
    u16* Vb    = (u16*)(ws + 134217728);
    u16* Vtb   = (u16*)(ws + 167772160);

    cvt_x<<<16384, 256, 0, stream>>>(x, xb);
    transpose_wall<<<dim3(32, 32, 4), dim3(64, 4), 0, stream>>>(wq, wk, wv, wo, wqkvb, wob);

    gemm_bt<0><<<dim3(48, 64), 256, 0, stream>>>(xb, wqkvb, Qb, Kb, Vb, nullptr, cosb, sinb);
    transpose_v<<<dim3(32, 2, 64), dim3(64, 4), 0, stream>>>(Vb, Vtb);
    attn_kernel<<<1024, 256, 0, stream>>>(Qb, Kb, Vtb, AO);
    gemm_bt<1><<<dim3(16, 64), 256, 0, stream>>>(AO, wob, nullptr, nullptr, nullptr, out, cosb, sinb);
}

// Round 4
// 713.542 us; speedup vs baseline: 1.0845x; 1.0845x over previous
//
#include <hip/hip_runtime.h>
#include <cstdint>
#include <cstddef>

typedef unsigned short u16;
using bf16x8  = __attribute__((ext_vector_type(8))) short;
using floatx4 = __attribute__((ext_vector_type(4))) float;

// ---------- helpers ----------
__device__ __forceinline__ u16 f2bf(float f) {
    union { float f; unsigned u; } v; v.f = f;
    unsigned r = v.u + 0x7fffu + ((v.u >> 16) & 1u);   // RNE
    return (u16)(r >> 16);
}
__device__ __forceinline__ float bf2f(u16 h) {
    union { unsigned u; float f; } v; v.u = ((unsigned)h) << 16; return v.f;
}
__device__ __forceinline__ floatx4 mfma16(bf16x8 a, bf16x8 b, floatx4 c) {
    return __builtin_amdgcn_mfma_f32_16x16x32_bf16(a, b, c, 0, 0, 0);
}
using gptr_t = const __attribute__((address_space(1))) unsigned int*;
using lptr_t = __attribute__((address_space(3))) unsigned int*;
__device__ __forceinline__ void lds16(const void* g, void* l) {
    __builtin_amdgcn_global_load_lds((gptr_t)g, (lptr_t)l, 16, 0, 0);
}

#define ATT_SCALE 0.1275758218522532f   // log2(e) / sqrt(128)

// ---------- 1. convert x f32 -> bf16 ----------
__global__ __launch_bounds__(256) void cvt_x(const float* __restrict__ x, u16* __restrict__ xb) {
    size_t i = ((size_t)blockIdx.x * 256 + threadIdx.x) * 4;
    float4 v = *(const float4*)&x[i];
    ushort4 r; r.x = f2bf(v.x); r.y = f2bf(v.y); r.z = f2bf(v.z); r.w = f2bf(v.w);
    *(ushort4*)&xb[i] = r;
}

// ---------- 2. transpose+convert all 4 weights f32 [2048][2048] -> bf16 [n][k] ----------
__global__ __launch_bounds__(256) void transpose_wall(const float* __restrict__ wq, const float* __restrict__ wk,
                                                      const float* __restrict__ wv, const float* __restrict__ wo,
                                                      u16* __restrict__ wqkvb, u16* __restrict__ wob) {
    __shared__ float t[64][65];
    const int z = blockIdx.z;
    const float* in = (z == 0) ? wq : (z == 1) ? wk : (z == 2) ? wv : wo;
    u16* out = (z < 3) ? (wqkvb + (size_t)z * 2048 * 2048) : wob;
    int k0 = blockIdx.x * 64, n0 = blockIdx.y * 64;
    int tx = threadIdx.x, ty = threadIdx.y;   // (64,4)
#pragma unroll
    for (int i = 0; i < 16; ++i) {
        int r = i * 4 + ty;
        t[r][tx] = in[(size_t)(k0 + r) * 2048 + n0 + tx];
    }
    __syncthreads();
#pragma unroll
    for (int i = 0; i < 16; ++i) {
        int r = i * 4 + ty;
        out[(size_t)(n0 + r) * 2048 + k0 + tx] = f2bf(t[tx][r]);
    }
}

// ---------- 3. main GEMM (A[m][k] bf16, B^T[n][k] bf16), 128x128 tile, BK=64 ----------
// MODE 0: QKV projection -> Q,K [b,h,s,d] bf16 ; V stored TRANSPOSED [b,h,d,s] bf16 (vectorized)
// MODE 1: output projection, f32 into d_out.
template <int MODE>
__global__ __launch_bounds__(256) void gemm_bt(const u16* __restrict__ A, const u16* __restrict__ B,
                                               u16* __restrict__ Qo, u16* __restrict__ Ko, u16* __restrict__ Vt,
                                               float* __restrict__ Co) {
    __shared__ __align__(16) u16 As[128 * 64];
    __shared__ __align__(16) u16 Bs[128 * 64];
    const int m0 = blockIdx.y << 7;
    const int n0 = blockIdx.x << 7;
    const int tid = threadIdx.x;
    const int w = tid >> 6, lane = tid & 63;
    const int wm = w >> 1, wn = w & 1;
    const int m16 = lane & 15, q4 = lane >> 4;

    floatx4 acc[4][4];
#pragma unroll
    for (int r = 0; r < 4; ++r)
#pragma unroll
        for (int c = 0; c < 4; ++c) acc[r][c] = (floatx4)0.0f;

    const u16* Abase = A + (size_t)(m0 + w * 32 + (lane >> 3)) * 2048 + (lane & 7) * 8;
    const u16* Bbase = B + (size_t)(n0 + w * 32 + (lane >> 3)) * 2048 + (lane & 7) * 8;
    u16* lA = As + (w * 32) * 64;
    u16* lB = Bs + (w * 32) * 64;

    for (int kt = 0; kt < 32; ++kt) {
        __syncthreads();
        const u16* ga = Abase + kt * 64;
        const u16* gb = Bbase + kt * 64;
#pragma unroll
        for (int t = 0; t < 4; ++t) {
            lds16(ga + (size_t)t * 8 * 2048, lA + t * 8 * 64);
            lds16(gb + (size_t)t * 8 * 2048, lB + t * 8 * 64);
        }
        __syncthreads();
#pragma unroll
        for (int kk = 0; kk < 2; ++kk) {
            bf16x8 af[4], bfr[4];
#pragma unroll
            for (int r = 0; r < 4; ++r)
                af[r] = *(const bf16x8*)&As[(wm * 64 + r * 16 + m16) * 64 + kk * 32 + q4 * 8];
#pragma unroll
            for (int c = 0; c < 4; ++c)
                bfr[c] = *(const bf16x8*)&Bs[(wn * 64 + c * 16 + m16) * 64 + kk * 32 + q4 * 8];
#pragma unroll
            for (int r = 0; r < 4; ++r)
#pragma unroll
                for (int c = 0; c < 4; ++c)
                    acc[r][c] = mfma16(af[r], bfr[c], acc[r][c]);
        }
    }

    if (MODE == 0) {
        const int which = n0 >> 11;           // 0=Q 1=K 2=V
        const int h = (n0 >> 7) & 15;
        if (which < 2) {
            u16* dst = (which == 0) ? Qo : Ko;
#pragma unroll
            for (int r = 0; r < 4; ++r) {
#pragma unroll
                for (int c = 0; c < 4; ++c) {
                    int d = wn * 64 + c * 16 + m16;
                    int mbase = m0 + wm * 64 + r * 16 + q4 * 4;
#pragma unroll
                    for (int i = 0; i < 4; ++i) {
                        int mm = mbase + i;
                        int b = mm >> 11, s = mm & 2047;
                        dst[((size_t)((b * 16 + h) * 2048 + s) << 7) + d] = f2bf(acc[r][c][i]);
                    }
                }
            }
        } else {
            // V stored transposed: Vt[b,h][d][s]; 4 consecutive s -> ushort4
#pragma unroll
            for (int r = 0; r < 4; ++r) {
#pragma unroll
                for (int c = 0; c < 4; ++c) {
                    int d = wn * 64 + c * 16 + m16;
                    int mbase = m0 + wm * 64 + r * 16 + q4 * 4;
                    int b = mbase >> 11, s = mbase & 2047;
                    ushort4 pk;
                    pk.x = f2bf(acc[r][c][0]); pk.y = f2bf(acc[r][c][1]);
                    pk.z = f2bf(acc[r][c][2]); pk.w = f2bf(acc[r][c][3]);
                    *(ushort4*)&Vt[((size_t)((b * 16 + h) * 128 + d)) * 2048 + s] = pk;
                }
            }
        }
    } else {
#pragma unroll
        for (int r = 0; r < 4; ++r) {
#pragma unroll
            for (int c = 0; c < 4; ++c) {
                int n = n0 + wn * 64 + c * 16 + m16;
                int mbase = m0 + wm * 64 + r * 16 + q4 * 4;
#pragma unroll
                for (int i = 0; i < 4; ++i)
                    Co[(size_t)(mbase + i) * 2048 + n] = acc[r][c][i];
            }
        }
    }
}

// ---------- 4. RoPE in place on Q,K (vectorized x4); Q pre-scaled by log2(e)/sqrt(HD) ----------
__global__ __launch_bounds__(256) void rope_qk(u16* __restrict__ Q, u16* __restrict__ K,
                                               const float* __restrict__ cosb, const float* __restrict__ sinb) {
    int t = blockIdx.x * 256 + threadIdx.x;   // B*H*S*16 threads
    int d4 = (t & 15) * 4;
    int row = t >> 4;
    int s = row & 2047;
    float4 cs = *(const float4*)&cosb[s * 64 + d4];
    float4 sn = *(const float4*)&sinb[s * 64 + d4];
    size_t base = (size_t)row * 128;
    ushort4 qlo = *(ushort4*)&Q[base + d4];
    ushort4 qhi = *(ushort4*)&Q[base + 64 + d4];
    ushort4 klo = *(ushort4*)&K[base + d4];
    ushort4 khi = *(ushort4*)&K[base + 64 + d4];
    float ql[4] = {bf2f(qlo.x), bf2f(qlo.y), bf2f(qlo.z), bf2f(qlo.w)};
    float qh[4] = {bf2f(qhi.x), bf2f(qhi.y), bf2f(qhi.z), bf2f(qhi.w)};
    float kl[4] = {bf2f(klo.x), bf2f(klo.y), bf2f(klo.z), bf2f(klo.w)};
    float kh[4] = {bf2f(khi.x), bf2f(khi.y), bf2f(khi.z), bf2f(khi.w)};
    float c[4] = {cs.x, cs.y, cs.z, cs.w};
    float n[4] = {sn.x, sn.y, sn.z, sn.w};
    ushort4 o0, o1, o2, o3;
    u16* p0 = &o0.x; u16* p1 = &o1.x; u16* p2 = &o2.x; u16* p3 = &o3.x;
#pragma unroll
    for (int i = 0; i < 4; ++i) {
        p0[i] = f2bf((ql[i] * c[i] - qh[i] * n[i]) * ATT_SCALE);
        p1[i] = f2bf((qh[i] * c[i] + ql[i] * n[i]) * ATT_SCALE);
        p2[i] = f2bf(kl[i] * c[i] - kh[i] * n[i]);
        p3[i] = f2bf(kh[i] * c[i] + kl[i] * n[i]);
    }
    *(ushort4*)&Q[base + d4]      = o0;
    *(ushort4*)&Q[base + 64 + d4] = o1;
    *(ushort4*)&K[base + d4]      = o2;
    *(ushort4*)&K[base + 64 + d4] = o3;
}

// ---------- 5. flash attention v4: 512 thr / 8 waves, BQ=256, 32 q-rows per wave ----------
// LDS-staged K and V^T tiles (R2 structure), S^T = K Q^T lane-local softmax.
// Q pre-scaled. Q,K: [b,h,s,128]; VT: [b,h,128,s]; AO: [b,s,h*128+d]
__global__ __launch_bounds__(512) void attn_kernel(const u16* __restrict__ Q, const u16* __restrict__ K,
                                                   const u16* __restrict__ VT, u16* __restrict__ AO) {
    __shared__ __align__(16) u16 ks[64 * 136];    // K-tile  [k 64][d 128+8]
    __shared__ __align__(16) u16 vts[128 * 72];   // V^T     [d 128][s 64+8]
    __shared__ __align__(16) u16 ps[256 * 72];    // P       [q 256][k 64+8]
    static const int iqmap[8] = {7, 6, 5, 4, 0, 1, 2, 3};  // (bx, bx+256) pairs balance
    const int bx = blockIdx.x;
    const int iq = iqmap[bx >> 6];
    const int bh = bx & 63;
    const int b = bh >> 4, h = bh & 15;
    const u16* Qg = Q  + (size_t)bh * (2048 * 128);
    const u16* Kg = K  + (size_t)bh * (2048 * 128);
    const u16* Vg = VT + (size_t)bh * (128 * 2048);
    const int tid = threadIdx.x, w = tid >> 6, lane = tid & 63;
    const int m16 = lane & 15, q4 = lane >> 4;
    const int jn = 4 * iq + 4;

    // wave w owns q-rows [iq*256 + w*32, +32): two 16-row tiles (rm)
    const int qrow = iq * 256 + w * 32;
    bf16x8 qf[2][4];
#pragma unroll
    for (int rm = 0; rm < 2; ++rm)
#pragma unroll
        for (int kk = 0; kk < 4; ++kk)
            qf[rm][kk] = *(const bf16x8*)&Qg[(size_t)(qrow + rm * 16 + m16) * 128 + kk * 32 + q4 * 8];

    floatx4 o[2][8];
#pragma unroll
    for (int rm = 0; rm < 2; ++rm)
#pragma unroll
        for (int c = 0; c < 8; ++c) o[rm][c] = (floatx4)0.0f;
    float mrow[2] = {-1e30f, -1e30f}, lrow[2] = {0.0f, 0.0f};

    for (int j = 0; j < jn; ++j) {
        __syncthreads();                          // prev iter done with ks/vts
        // stage K tile (64x128) and V^T tile (128x64): 1024 uint4 chunks each, 2/thread
#pragma unroll
        for (int u = 0; u < 2; ++u) {
            int id = u * 512 + tid;
            int kr = id >> 4, kc = id & 15;
            uint4 kv = *(const uint4*)&Kg[(size_t)(j * 64 + kr) * 128 + kc * 8];
            int vr = id >> 3, vc = id & 7;
            uint4 vv = *(const uint4*)&Vg[(size_t)vr * 2048 + j * 64 + vc * 8];
            *(uint4*)&ks[kr * 136 + kc * 8] = kv;
            *(uint4*)&vts[vr * 72 + vc * 8] = vv;
        }
        __syncthreads();

        // S^T = K Q^T : rows k (4 tiles of 16), cols q (16 per rm)
        floatx4 sacc[2][4];
#pragma unroll
        for (int rm = 0; rm < 2; ++rm)
#pragma unroll
            for (int r = 0; r < 4; ++r) sacc[rm][r] = (floatx4)0.0f;
#pragma unroll
        for (int kk = 0; kk < 4; ++kk) {
            bf16x8 kb[4];
#pragma unroll
            for (int r = 0; r < 4; ++r)
                kb[r] = *(const bf16x8*)&ks[(r * 16 + m16) * 136 + kk * 32 + q4 * 8];
#pragma unroll
            for (int rm = 0; rm < 2; ++rm)
#pragma unroll
                for (int r = 0; r < 4; ++r)
                    sacc[rm][r] = mfma16(kb[r], qf[rm][kk], sacc[rm][r]);
        }

        // causal mask: lane holds S^T[k = j*64 + r*16 + q4*4 + i][q = qrow + rm*16 + m16]
        if (j >= 4 * iq) {
#pragma unroll
            for (int rm = 0; rm < 2; ++rm) {
                const int qg = qrow + rm * 16 + m16;
#pragma unroll
                for (int r = 0; r < 4; ++r)
#pragma unroll
                    for (int i = 0; i < 4; ++i) {
                        int kg = j * 64 + r * 16 + q4 * 4 + i;
                        if (kg > qg) sacc[rm][r][i] = -1e30f;
                    }
            }
        }

#pragma unroll
        for (int rm = 0; rm < 2; ++rm) {
            float pmax = -1e30f;
#pragma unroll
            for (int r = 0; r < 4; ++r)
#pragma unroll
                for (int i = 0; i < 4; ++i) pmax = fmaxf(pmax, sacc[rm][r][i]);
            pmax = fmaxf(pmax, __shfl_xor(pmax, 16));
            pmax = fmaxf(pmax, __shfl_xor(pmax, 32));
            float mnew = fmaxf(mrow[rm], pmax);
            float alpha = __builtin_amdgcn_exp2f(mrow[rm] - mnew);
            mrow[rm] = mnew;

            float psum = 0.0f;
#pragma unroll
            for (int r = 0; r < 4; ++r) {
                float p0 = __builtin_amdgcn_exp2f(sacc[rm][r][0] - mnew);
                float p1 = __builtin_amdgcn_exp2f(sacc[rm][r][1] - mnew);
                float p2 = __builtin_amdgcn_exp2f(sacc[rm][r][2] - mnew);
                float p3 = __builtin_amdgcn_exp2f(sacc[rm][r][3] - mnew);
                psum += (p0 + p1) + (p2 + p3);
                ushort4 pk; pk.x = f2bf(p0); pk.y = f2bf(p1); pk.z = f2bf(p2); pk.w = f2bf(p3);
                *(ushort4*)&ps[(w * 32 + rm * 16 + m16) * 72 + r * 16 + q4 * 4] = pk;
            }
            psum += __shfl_xor(psum, 16);
            psum += __shfl_xor(psum, 32);
            lrow[rm] = lrow[rm] * alpha + psum;

            float abc[4];
#pragma unroll
            for (int i = 0; i < 4; ++i) abc[i] = __shfl(alpha, q4 * 4 + i);
#pragma unroll
            for (int c = 0; c < 8; ++c)
#pragma unroll
                for (int i = 0; i < 4; ++i) o[rm][c][i] *= abc[i];
        }

        // O += P V : P wave-private rows from LDS, V^T from LDS; split c to limit live regs
#pragma unroll
        for (int kk = 0; kk < 2; ++kk) {
            bf16x8 pa[2];
#pragma unroll
            for (int rm = 0; rm < 2; ++rm)
                pa[rm] = *(const bf16x8*)&ps[(w * 32 + rm * 16 + m16) * 72 + kk * 32 + q4 * 8];
#pragma unroll
            for (int ch = 0; ch < 2; ++ch) {
                bf16x8 vb[4];
#pragma unroll
                for (int c = 0; c < 4; ++c)
                    vb[c] = *(const bf16x8*)&vts[((ch * 4 + c) * 16 + m16) * 72 + kk * 32 + q4 * 8];
#pragma unroll
                for (int rm = 0; rm < 2; ++rm)
#pragma unroll
                    for (int c = 0; c < 4; ++c)
                        o[rm][ch * 4 + c] = mfma16(pa[rm], vb[c], o[rm][ch * 4 + c]);
            }
        }
    }

    // epilogue: O row = q4*4+i (q-local), col d = c*16+m16; l lives at lane m16=q -> shfl
#pragma unroll
    for (int rm = 0; rm < 2; ++rm) {
        float linv = __builtin_amdgcn_rcpf(lrow[rm]);
        float li[4];
#pragma unroll
        for (int i = 0; i < 4; ++i) li[i] = __shfl(linv, q4 * 4 + i);
#pragma unroll
        for (int c = 0; c < 8; ++c)
#pragma unroll
            for (int i = 0; i < 4; ++i) {
                int s = qrow + rm * 16 + q4 * 4 + i;
                int d = c * 16 + m16;
                AO[((size_t)(b * 2048 + s)) * 2048 + h * 128 + d] = f2bf(o[rm][c][i] * li[i]);
            }
    }
}

// ---------- launch ----------
extern "C" void kernel_launch(void* const* d_in, const int* in_sizes, int n_in,
                              void* d_out, int out_size, void* d_ws, size_t ws_size,
                              hipStream_t stream) {
    const float* x    = (const float*)d_in[0];
    const float* wq   = (const float*)d_in[1];
    const float* wk   = (const float*)d_in[2];
    const float* wv   = (const float*)d_in[3];
    const float* wo   = (const float*)d_in[4];
    const float* cosb = (const float*)d_in[5];
    const float* sinb = (const float*)d_in[6];
    float* out = (float*)d_out;

    char* ws = (char*)d_ws;
    u16* xb    = (u16*)(ws);                          // 32 MiB
    u16* AO    = xb;                                  // alias: xb dead after QKV GEMM
    u16* wqkvb = (u16*)(ws + 33554432);               // 24 MiB
    u16* wob   = (u16*)(ws + 58720256);               // 8 MiB
    u16* Qb    = (u16*)(ws + 67108864);               // 32 MiB
    u16* Kb    = (u16*)(ws + 100663296);              // 32 MiB
    u16* Vtb   = (u16*)(ws + 134217728);              // 32 MiB (V stored transposed)

    cvt_x<<<16384, 256, 0, stream>>>(x, xb);
    transpose_wall<<<dim3(32, 32, 4), dim3(64, 4), 0, stream>>>(wq, wk, wv, wo, wqkvb, wob);

    gemm_bt<0><<<dim3(48, 64), 256, 0, stream>>>(xb, wqkvb, Qb, Kb, Vtb, nullptr);
    rope_qk<<<8192, 256, 0, stream>>>(Qb, Kb, cosb, sinb);
    attn_kernel<<<512, 512, 0, stream>>>(Qb, Kb, Vtb, AO);
    gemm_bt<1><<<dim3(16, 64), 256, 0, stream>>>(AO, wob, nullptr, nullptr, nullptr, out);
}

// Round 5
// 631.434 us; speedup vs baseline: 1.2256x; 1.1300x over previous
//
#include <hip/hip_runtime.h>
#include <cstdint>
#include <cstddef>

typedef unsigned short u16;
using bf16x8  = __attribute__((ext_vector_type(8))) short;
using floatx4 = __attribute__((ext_vector_type(4))) float;

// ---------- helpers ----------
__device__ __forceinline__ u16 f2bf(float f) {
    union { float f; unsigned u; } v; v.f = f;
    unsigned r = v.u + 0x7fffu + ((v.u >> 16) & 1u);   // RNE
    return (u16)(r >> 16);
}
__device__ __forceinline__ float bf2f(u16 h) {
    union { unsigned u; float f; } v; v.u = ((unsigned)h) << 16; return v.f;
}
__device__ __forceinline__ floatx4 mfma16(bf16x8 a, bf16x8 b, floatx4 c) {
    return __builtin_amdgcn_mfma_f32_16x16x32_bf16(a, b, c, 0, 0, 0);
}
using gptr_t = const __attribute__((address_space(1))) unsigned int*;
using lptr_t = __attribute__((address_space(3))) unsigned int*;
__device__ __forceinline__ void lds16(const void* g, void* l) {
    __builtin_amdgcn_global_load_lds((gptr_t)g, (lptr_t)l, 16, 0, 0);
}

#define ATT_SCALE 0.1275758218522532f   // log2(e) / sqrt(128)

// ---------- 1. convert x f32 -> bf16 ----------
__global__ __launch_bounds__(256) void cvt_x(const float* __restrict__ x, u16* __restrict__ xb) {
    size_t i = ((size_t)blockIdx.x * 256 + threadIdx.x) * 4;
    float4 v = *(const float4*)&x[i];
    ushort4 r; r.x = f2bf(v.x); r.y = f2bf(v.y); r.z = f2bf(v.z); r.w = f2bf(v.w);
    *(ushort4*)&xb[i] = r;
}

// ---------- 2. transpose+convert all 4 weights f32 [2048][2048] -> bf16 [n][k] ----------
__global__ __launch_bounds__(256) void transpose_wall(const float* __restrict__ wq, const float* __restrict__ wk,
                                                      const float* __restrict__ wv, const float* __restrict__ wo,
                                                      u16* __restrict__ wqkvb, u16* __restrict__ wob) {
    __shared__ float t[64][65];
    const int z = blockIdx.z;
    const float* in = (z == 0) ? wq : (z == 1) ? wk : (z == 2) ? wv : wo;
    u16* out = (z < 3) ? (wqkvb + (size_t)z * 2048 * 2048) : wob;
    int k0 = blockIdx.x * 64, n0 = blockIdx.y * 64;
    int tx = threadIdx.x, ty = threadIdx.y;   // (64,4)
#pragma unroll
    for (int i = 0; i < 16; ++i) {
        int r = i * 4 + ty;
        t[r][tx] = in[(size_t)(k0 + r) * 2048 + n0 + tx];
    }
    __syncthreads();
#pragma unroll
    for (int i = 0; i < 16; ++i) {
        int r = i * 4 + ty;
        out[(size_t)(n0 + r) * 2048 + k0 + tx] = f2bf(t[tx][r]);
    }
}

// ---------- 3. main GEMM (A[m][k] bf16, B^T[n][k] bf16), 128x128 tile, BK=64 ----------
// MODE 0: QKV projection -> Q,K [b,h,s,d] bf16 ; V stored TRANSPOSED [b,h,d,s] bf16 (vectorized)
// MODE 1: output projection, f32 into d_out.
// __launch_bounds__(256,5): cap VGPR at ~102 so the K-loop keeps the LDS-capped 5 blocks/CU;
// epilogue spills (once per block) are cheap. R4's 116-VGPR epilogue cost 6->4 waves/SIMD = +72us.
template <int MODE>
__global__ __launch_bounds__(256, 5) void gemm_bt(const u16* __restrict__ A, const u16* __restrict__ B,
                                                  u16* __restrict__ Qo, u16* __restrict__ Ko, u16* __restrict__ Vt,
                                                  float* __restrict__ Co) {
    __shared__ __align__(16) u16 As[128 * 64];
    __shared__ __align__(16) u16 Bs[128 * 64];
    const int m0 = blockIdx.y << 7;
    const int n0 = blockIdx.x << 7;
    const int tid = threadIdx.x;
    const int w = tid >> 6, lane = tid & 63;
    const int wm = w >> 1, wn = w & 1;
    const int m16 = lane & 15, q4 = lane >> 4;

    floatx4 acc[4][4];
#pragma unroll
    for (int r = 0; r < 4; ++r)
#pragma unroll
        for (int c = 0; c < 4; ++c) acc[r][c] = (floatx4)0.0f;

    const u16* Abase = A + (size_t)(m0 + w * 32 + (lane >> 3)) * 2048 + (lane & 7) * 8;
    const u16* Bbase = B + (size_t)(n0 + w * 32 + (lane >> 3)) * 2048 + (lane & 7) * 8;
    u16* lA = As + (w * 32) * 64;
    u16* lB = Bs + (w * 32) * 64;

    for (int kt = 0; kt < 32; ++kt) {
        __syncthreads();
        const u16* ga = Abase + kt * 64;
        const u16* gb = Bbase + kt * 64;
#pragma unroll
        for (int t = 0; t < 4; ++t) {
            lds16(ga + (size_t)t * 8 * 2048, lA + t * 8 * 64);
            lds16(gb + (size_t)t * 8 * 2048, lB + t * 8 * 64);
        }
        __syncthreads();
#pragma unroll
        for (int kk = 0; kk < 2; ++kk) {
            bf16x8 af[4], bfr[4];
#pragma unroll
            for (int r = 0; r < 4; ++r)
                af[r] = *(const bf16x8*)&As[(wm * 64 + r * 16 + m16) * 64 + kk * 32 + q4 * 8];
#pragma unroll
            for (int c = 0; c < 4; ++c)
                bfr[c] = *(const bf16x8*)&Bs[(wn * 64 + c * 16 + m16) * 64 + kk * 32 + q4 * 8];
#pragma unroll
            for (int r = 0; r < 4; ++r)
#pragma unroll
                for (int c = 0; c < 4; ++c)
                    acc[r][c] = mfma16(af[r], bfr[c], acc[r][c]);
        }
    }

    if (MODE == 0) {
        const int which = n0 >> 11;           // 0=Q 1=K 2=V
        const int h = (n0 >> 7) & 15;
        if (which < 2) {
            u16* dst = (which == 0) ? Qo : Ko;
#pragma unroll
            for (int r = 0; r < 4; ++r) {
#pragma unroll
                for (int c = 0; c < 4; ++c) {
                    int d = wn * 64 + c * 16 + m16;
                    int mbase = m0 + wm * 64 + r * 16 + q4 * 4;
#pragma unroll
                    for (int i = 0; i < 4; ++i) {
                        int mm = mbase + i;
                        int b = mm >> 11, s = mm & 2047;
                        dst[((size_t)((b * 16 + h) * 2048 + s) << 7) + d] = f2bf(acc[r][c][i]);
                    }
                }
            }
        } else {
            // V stored transposed: Vt[b,h][d][s]; 4 consecutive s -> ushort4
#pragma unroll
            for (int r = 0; r < 4; ++r) {
#pragma unroll
                for (int c = 0; c < 4; ++c) {
                    int d = wn * 64 + c * 16 + m16;
                    int mbase = m0 + wm * 64 + r * 16 + q4 * 4;
                    int b = mbase >> 11, s = mbase & 2047;
                    ushort4 pk;
                    pk.x = f2bf(acc[r][c][0]); pk.y = f2bf(acc[r][c][1]);
                    pk.z = f2bf(acc[r][c][2]); pk.w = f2bf(acc[r][c][3]);
                    *(ushort4*)&Vt[((size_t)((b * 16 + h) * 128 + d)) * 2048 + s] = pk;
                }
            }
        }
    } else {
#pragma unroll
        for (int r = 0; r < 4; ++r) {
#pragma unroll
            for (int c = 0; c < 4; ++c) {
                int n = n0 + wn * 64 + c * 16 + m16;
                int mbase = m0 + wm * 64 + r * 16 + q4 * 4;
#pragma unroll
                for (int i = 0; i < 4; ++i)
                    Co[(size_t)(mbase + i) * 2048 + n] = acc[r][c][i];
            }
        }
    }
}

// ---------- 4. RoPE in place on Q,K (vectorized x4); Q pre-scaled by log2(e)/sqrt(HD) ----------
__global__ __launch_bounds__(256) void rope_qk(u16* __restrict__ Q, u16* __restrict__ K,
                                               const float* __restrict__ cosb, const float* __restrict__ sinb) {
    int t = blockIdx.x * 256 + threadIdx.x;   // B*H*S*16 threads
    int d4 = (t & 15) * 4;
    int row = t >> 4;
    int s = row & 2047;
    float4 cs = *(const float4*)&cosb[s * 64 + d4];
    float4 sn = *(const float4*)&sinb[s * 64 + d4];
    size_t base = (size_t)row * 128;
    ushort4 qlo = *(ushort4*)&Q[base + d4];
    ushort4 qhi = *(ushort4*)&Q[base + 64 + d4];
    ushort4 klo = *(ushort4*)&K[base + d4];
    ushort4 khi = *(ushort4*)&K[base + 64 + d4];
    float ql[4] = {bf2f(qlo.x), bf2f(qlo.y), bf2f(qlo.z), bf2f(qlo.w)};
    float qh[4] = {bf2f(qhi.x), bf2f(qhi.y), bf2f(qhi.z), bf2f(qhi.w)};
    float kl[4] = {bf2f(klo.x), bf2f(klo.y), bf2f(klo.z), bf2f(klo.w)};
    float kh[4] = {bf2f(khi.x), bf2f(khi.y), bf2f(khi.z), bf2f(khi.w)};
    float c[4] = {cs.x, cs.y, cs.z, cs.w};
    float n[4] = {sn.x, sn.y, sn.z, sn.w};
    ushort4 o0, o1, o2, o3;
    u16* p0 = &o0.x; u16* p1 = &o1.x; u16* p2 = &o2.x; u16* p3 = &o3.x;
#pragma unroll
    for (int i = 0; i < 4; ++i) {
        p0[i] = f2bf((ql[i] * c[i] - qh[i] * n[i]) * ATT_SCALE);
        p1[i] = f2bf((qh[i] * c[i] + ql[i] * n[i]) * ATT_SCALE);
        p2[i] = f2bf(kl[i] * c[i] - kh[i] * n[i]);
        p3[i] = f2bf(kh[i] * c[i] + kl[i] * n[i]);
    }
    *(ushort4*)&Q[base + d4]      = o0;
    *(ushort4*)&Q[base + 64 + d4] = o1;
    *(ushort4*)&K[base + d4]      = o2;
    *(ushort4*)&K[base + 64 + d4] = o3;
}

// ---------- 5. flash attention v4: 512 thr / 8 waves, BQ=256, 32 q-rows per wave ----------
// LDS-staged K and V^T tiles, S^T = K Q^T lane-local softmax.
// Q pre-scaled. Q,K: [b,h,s,128]; VT: [b,h,128,s]; AO: [b,s,h*128+d]
__global__ __launch_bounds__(512) void attn_kernel(const u16* __restrict__ Q, const u16* __restrict__ K,
                                                   const u16* __restrict__ VT, u16* __restrict__ AO) {
    __shared__ __align__(16) u16 ks[64 * 136];    // K-tile  [k 64][d 128+8]
    __shared__ __align__(16) u16 vts[128 * 72];   // V^T     [d 128][s 64+8]
    __shared__ __align__(16) u16 ps[256 * 72];    // P       [q 256][k 64+8]
    static const int iqmap[8] = {7, 6, 5, 4, 0, 1, 2, 3};  // (bx, bx+256) pairs balance
    const int bx = blockIdx.x;
    const int iq = iqmap[bx >> 6];
    const int bh = bx & 63;
    const int b = bh >> 4, h = bh & 15;
    const u16* Qg = Q  + (size_t)bh * (2048 * 128);
    const u16* Kg = K  + (size_t)bh * (2048 * 128);
    const u16* Vg = VT + (size_t)bh * (128 * 2048);
    const int tid = threadIdx.x, w = tid >> 6, lane = tid & 63;
    const int m16 = lane & 15, q4 = lane >> 4;
    const int jn = 4 * iq + 4;

    // wave w owns q-rows [iq*256 + w*32, +32): two 16-row tiles (rm)
    const int qrow = iq * 256 + w * 32;
    bf16x8 qf[2][4];
#pragma unroll
    for (int rm = 0; rm < 2; ++rm)
#pragma unroll
        for (int kk = 0; kk < 4; ++kk)
            qf[rm][kk] = *(const bf16x8*)&Qg[(size_t)(qrow + rm * 16 + m16) * 128 + kk * 32 + q4 * 8];

    floatx4 o[2][8];
#pragma unroll
    for (int rm = 0; rm < 2; ++rm)
#pragma unroll
        for (int c = 0; c < 8; ++c) o[rm][c] = (floatx4)0.0f;
    float mrow[2] = {-1e30f, -1e30f}, lrow[2] = {0.0f, 0.0f};

    for (int j = 0; j < jn; ++j) {
        __syncthreads();                          // prev iter done with ks/vts
        // stage K tile (64x128) and V^T tile (128x64): 1024 uint4 chunks each, 2/thread
#pragma unroll
        for (int u = 0; u < 2; ++u) {
            int id = u * 512 + tid;
            int kr = id >> 4, kc = id & 15;
            uint4 kv = *(const uint4*)&Kg[(size_t)(j * 64 + kr) * 128 + kc * 8];
            int vr = id >> 3, vc = id & 7;
            uint4 vv = *(const uint4*)&Vg[(size_t)vr * 2048 + j * 64 + vc * 8];
            *(uint4*)&ks[kr * 136 + kc * 8] = kv;
            *(uint4*)&vts[vr * 72 + vc * 8] = vv;
        }
        __syncthreads();

        // S^T = K Q^T : rows k (4 tiles of 16), cols q (16 per rm)
        floatx4 sacc[2][4];
#pragma unroll
        for (int rm = 0; rm < 2; ++rm)
#pragma unroll
            for (int r = 0; r < 4; ++r) sacc[rm][r] = (floatx4)0.0f;
#pragma unroll
        for (int kk = 0; kk < 4; ++kk) {
            bf16x8 kb[4];
#pragma unroll
            for (int r = 0; r < 4; ++r)
                kb[r] = *(const bf16x8*)&ks[(r * 16 + m16) * 136 + kk * 32 + q4 * 8];
#pragma unroll
            for (int rm = 0; rm < 2; ++rm)
#pragma unroll
                for (int r = 0; r < 4; ++r)
                    sacc[rm][r] = mfma16(kb[r], qf[rm][kk], sacc[rm][r]);
        }

        // causal mask: lane holds S^T[k = j*64 + r*16 + q4*4 + i][q = qrow + rm*16 + m16]
        if (j >= 4 * iq) {
#pragma unroll
            for (int rm = 0; rm < 2; ++rm) {
                const int qg = qrow + rm * 16 + m16;
#pragma unroll
                for (int r = 0; r < 4; ++r)
#pragma unroll
                    for (int i = 0; i < 4; ++i) {
                        int kg = j * 64 + r * 16 + q4 * 4 + i;
                        if (kg > qg) sacc[rm][r][i] = -1e30f;
                    }
            }
        }

#pragma unroll
        for (int rm = 0; rm < 2; ++rm) {
            float pmax = -1e30f;
#pragma unroll
            for (int r = 0; r < 4; ++r)
#pragma unroll
                for (int i = 0; i < 4; ++i) pmax = fmaxf(pmax, sacc[rm][r][i]);
            pmax = fmaxf(pmax, __shfl_xor(pmax, 16));
            pmax = fmaxf(pmax, __shfl_xor(pmax, 32));
            float mnew = fmaxf(mrow[rm], pmax);
            float alpha = __builtin_amdgcn_exp2f(mrow[rm] - mnew);
            mrow[rm] = mnew;

            float psum = 0.0f;
#pragma unroll
            for (int r = 0; r < 4; ++r) {
                float p0 = __builtin_amdgcn_exp2f(sacc[rm][r][0] - mnew);
                float p1 = __builtin_amdgcn_exp2f(sacc[rm][r][1] - mnew);
                float p2 = __builtin_amdgcn_exp2f(sacc[rm][r][2] - mnew);
                float p3 = __builtin_amdgcn_exp2f(sacc[rm][r][3] - mnew);
                psum += (p0 + p1) + (p2 + p3);
                ushort4 pk; pk.x = f2bf(p0); pk.y = f2bf(p1); pk.z = f2bf(p2); pk.w = f2bf(p3);
                *(ushort4*)&ps[(w * 32 + rm * 16 + m16) * 72 + r * 16 + q4 * 4] = pk;
            }
            psum += __shfl_xor(psum, 16);
            psum += __shfl_xor(psum, 32);
            lrow[rm] = lrow[rm] * alpha + psum;

            float abc[4];
#pragma unroll
            for (int i = 0; i < 4; ++i) abc[i] = __shfl(alpha, q4 * 4 + i);
#pragma unroll
            for (int c = 0; c < 8; ++c)
#pragma unroll
                for (int i = 0; i < 4; ++i) o[rm][c][i] *= abc[i];
        }

        // O += P V : P wave-private rows from LDS, V^T from LDS; split c to limit live regs
#pragma unroll
        for (int kk = 0; kk < 2; ++kk) {
            bf16x8 pa[2];
#pragma unroll
            for (int rm = 0; rm < 2; ++rm)
                pa[rm] = *(const bf16x8*)&ps[(w * 32 + rm * 16 + m16) * 72 + kk * 32 + q4 * 8];
#pragma unroll
            for (int ch = 0; ch < 2; ++ch) {
                bf16x8 vb[4];
#pragma unroll
                for (int c = 0; c < 4; ++c)
                    vb[c] = *(const bf16x8*)&vts[((ch * 4 + c) * 16 + m16) * 72 + kk * 32 + q4 * 8];
#pragma unroll
                for (int rm = 0; rm < 2; ++rm)
#pragma unroll
                    for (int c = 0; c < 4; ++c)
                        o[rm][ch * 4 + c] = mfma16(pa[rm], vb[c], o[rm][ch * 4 + c]);
            }
        }
    }

    // epilogue: O row = q4*4+i (q-local), col d = c*16+m16; l lives at lane m16=q -> shfl
#pragma unroll
    for (int rm = 0; rm < 2; ++rm) {
        float linv = __builtin_amdgcn_rcpf(lrow[rm]);
        float li[4];
#pragma unroll
        for (int i = 0; i < 4; ++i) li[i] = __shfl(linv, q4 * 4 + i);
#pragma unroll
        for (int c = 0; c < 8; ++c)
#pragma unroll
            for (int i = 0; i < 4; ++i) {
                int s = qrow + rm * 16 + q4 * 4 + i;
                int d = c * 16 + m16;
                AO[((size_t)(b * 2048 + s)) * 2048 + h * 128 + d] = f2bf(o[rm][c][i] * li[i]);
            }
    }
}

// ---------- launch ----------
extern "C" void kernel_launch(void* const* d_in, const int* in_sizes, int n_in,
                              void* d_out, int out_size, void* d_ws, size_t ws_size,
                              hipStream_t stream) {
    const float* x    = (const float*)d_in[0];
    const float* wq   = (const float*)d_in[1];
    const float* wk   = (const float*)d_in[2];
    const float* wv   = (const float*)d_in[3];
    const float* wo   = (const float*)d_in[4];
    const float* cosb = (const float*)d_in[5];
    const float* sinb = (const float*)d_in[6];
    float* out = (float*)d_out;

    char* ws = (char*)d_ws;
    u16* xb    = (u16*)(ws);                          // 32 MiB
    u16* AO    = xb;                                  // alias: xb dead after QKV GEMM
    u16* wqkvb = (u16*)(ws + 33554432);               // 24 MiB
    u16* wob   = (u16*)(ws + 58720256);               // 8 MiB
    u16* Qb    = (u16*)(ws + 67108864);               // 32 MiB
    u16* Kb    = (u16*)(ws + 100663296);              // 32 MiB
    u16* Vtb   = (u16*)(ws + 134217728);              // 32 MiB (V stored transposed)

    cvt_x<<<16384, 256, 0, stream>>>(x, xb);
    transpose_wall<<<dim3(32, 32, 4), dim3(64, 4), 0, stream>>>(wq, wk, wv, wo, wqkvb, wob);

    gemm_bt<0><<<dim3(48, 64), 256, 0, stream>>>(xb, wqkvb, Qb, Kb, Vtb, nullptr);
    rope_qk<<<8192, 256, 0, stream>>>(Qb, Kb, cosb, sinb);
    attn_kernel<<<512, 512, 0, stream>>>(Qb, Kb, Vtb, AO);
    gemm_bt<1><<<dim3(16, 64), 256, 0, stream>>>(AO, wob, nullptr, nullptr, nullptr, out);
}